// Round 2
// baseline (2525.102 us; speedup 1.0000x reference)
//
#include <hip/hip_runtime.h>
#include <hip/hip_bf16.h>
#include <cstdint>
#include <cstddef>

// ---------------------------------------------------------------------------
// Transformer_78941498901000 — round 1: ws-size-adaptive chunked pipeline
// B=512 T=128 C=512 H=8 D=64 L=6 V=13, BT=65536
// d_out = logits f32 [851968] ++ loss f32 [1]
//
// ws layout (bytes):
//   x_bf  @ 0          : bf16 [BT,512]       67,108,864   (residual stream)
//   wqkvT @ 67,108,864 : bf16 [L][1536][512]  9,437,184   (n-major, k-minor)
//   woT   @ 76,546,048 : bf16 [L][512][512]   3,145,728
//   dyn   @ 79,691,776 : per-chunk qkv_c | tmp_c | hid_c  (6144 B per row)
// R = largest {65536..1024} with 79,691,776 + 6144*R <= ws_size
// ---------------------------------------------------------------------------

typedef __attribute__((ext_vector_type(8))) short short8;
typedef __attribute__((ext_vector_type(4))) float f32x4;

__device__ __forceinline__ float bf2f(ushort u) {
    return __uint_as_float(((unsigned int)u) << 16);
}
__device__ __forceinline__ ushort f2bf(float f) {
    unsigned int x = __float_as_uint(f);
    unsigned int r = (x + 0x7fffu + ((x >> 16) & 1u)) >> 16;  // RNE
    return (ushort)r;
}

// ---------------- weight prep: f32 [K][N] -> bf16 [N][K] -------------------
__global__ void prep_weights(const float* __restrict__ Wq, const float* __restrict__ Wk,
                             const float* __restrict__ Wv, const float* __restrict__ Wo,
                             ushort* __restrict__ wqkvT, ushort* __restrict__ woT) {
    const int QKV_TOT = 6 * 1536 * 512;   // 4,718,592
    const int O_TOT   = 6 * 512 * 512;    // 1,572,864
    size_t idx = (size_t)blockIdx.x * 256 + threadIdx.x;
    if (idx < (size_t)QKV_TOT) {
        int k = (int)(idx & 511);
        int n = (int)((idx >> 9) % 1536);
        int l = (int)(idx / (1536 * 512));
        size_t base = (size_t)l * 512 * 512 + (size_t)k * 512;
        float v;
        if (n < 512)        v = Wq[base + n];
        else if (n < 1024)  v = Wk[base + (n - 512)];
        else                v = Wv[base + (n - 1024)];
        wqkvT[idx] = f2bf(v);
    } else if (idx < (size_t)(QKV_TOT + O_TOT)) {
        size_t j = idx - QKV_TOT;
        int k = (int)(j & 511);
        int n = (int)((j >> 9) & 511);
        int l = (int)(j / (512 * 512));
        woT[j] = f2bf(Wo[(size_t)l * 512 * 512 + (size_t)k * 512 + n]);
    }
}

// ---------------- embedding: x = bf16(wte[tok] + wpe[t]) -------------------
__global__ __launch_bounds__(256) void embed_kernel(const int* __restrict__ tok,
                                                    const float* __restrict__ wte,
                                                    const float* __restrict__ wpe,
                                                    ushort* __restrict__ xbf) {
    size_t idx = (size_t)blockIdx.x * 256 + threadIdx.x;  // one short8 per thread
    size_t row = idx >> 6;              // 64 chunks of 8 per row
    int c8 = (int)(idx & 63);
    int t = (int)(row & 127);
    int v = tok[row];
    const float* ep = wte + (size_t)v * 512 + c8 * 8;
    const float* pp = wpe + (size_t)t * 512 + c8 * 8;
    float4 e0 = *(const float4*)ep, e1 = *(const float4*)(ep + 4);
    float4 p0 = *(const float4*)pp, p1 = *(const float4*)(pp + 4);
    float s[8] = {e0.x + p0.x, e0.y + p0.y, e0.z + p0.z, e0.w + p0.w,
                  e1.x + p1.x, e1.y + p1.y, e1.z + p1.z, e1.w + p1.w};
    short8 o;
    #pragma unroll
    for (int j = 0; j < 8; j++) o[j] = (short)f2bf(s[j]);
    *(short8*)(xbf + row * 512 + c8 * 8) = o;
}

// ---------------- bf16 MFMA GEMM: out = A[M,512] @ Bt[N,512]^T + bias ------
// MODE 0: bf16 out, 3-segment bias (qkv).  MODE 1: f32 out, single bias.
#define BM 128
#define BN 128
#define BKT 64

template<int MODE>
__global__ __launch_bounds__(256) void gemm_kernel(
    const ushort* __restrict__ A, const ushort* __restrict__ Bt, int N,
    const float* __restrict__ b0, const float* __restrict__ b1,
    const float* __restrict__ b2, ushort* __restrict__ obf, float* __restrict__ of) {
    __shared__ alignas(16) ushort As[BM * BKT];
    __shared__ alignas(16) ushort Bs[BN * BKT];
    const int tid = threadIdx.x;
    const int lane = tid & 63;
    const int wave = tid >> 6;
    const int m0 = blockIdx.x * BM;
    const int n0 = blockIdx.y * BN;
    const int wm = (wave >> 1) * 64;
    const int wn = (wave & 1) * 64;
    const int r = lane & 15;
    const int kq = (lane >> 4) * 8;
    f32x4 acc[4][4] = {};

    for (int k0 = 0; k0 < 512; k0 += BKT) {
        #pragma unroll
        for (int i = 0; i < 4; i++) {
            int ch = tid + i * 256;          // 1024 chunks of 16B per tile
            int row = ch >> 3, c8 = ch & 7;
            short8 va = *(const short8*)(A  + (size_t)(m0 + row) * 512 + k0 + c8 * 8);
            short8 vb = *(const short8*)(Bt + (size_t)(n0 + row) * 512 + k0 + c8 * 8);
            int boff = (row * 128 + c8 * 16) ^ ((row & 7) << 4);  // XOR swizzle (G4)
            *(short8*)((char*)As + boff) = va;
            *(short8*)((char*)Bs + boff) = vb;
        }
        __syncthreads();
        #pragma unroll
        for (int kk = 0; kk < BKT; kk += 32) {
            short8 af[4], bfr[4];
            #pragma unroll
            for (int m = 0; m < 4; m++) {
                int row = wm + m * 16 + r;
                int boff = (row * 128 + (kk + kq) * 2) ^ ((row & 7) << 4);
                af[m] = *(const short8*)((const char*)As + boff);
            }
            #pragma unroll
            for (int n = 0; n < 4; n++) {
                int row = wn + n * 16 + r;
                int boff = (row * 128 + (kk + kq) * 2) ^ ((row & 7) << 4);
                bfr[n] = *(const short8*)((const char*)Bs + boff);
            }
            #pragma unroll
            for (int m = 0; m < 4; m++)
                #pragma unroll
                for (int n = 0; n < 4; n++)
                    acc[m][n] = __builtin_amdgcn_mfma_f32_16x16x32_bf16(
                        af[m], bfr[n], acc[m][n], 0, 0, 0);
        }
        __syncthreads();
    }
    const int r4 = (lane >> 4) * 4;
    const int cc = lane & 15;
    #pragma unroll
    for (int m = 0; m < 4; m++) {
        #pragma unroll
        for (int n = 0; n < 4; n++) {
            int cg = n0 + wn + n * 16 + cc;
            float bias;
            if (MODE == 0)
                bias = (cg < 512) ? b0[cg] : (cg < 1024) ? b1[cg - 512] : b2[cg - 1024];
            else
                bias = b0[cg];
            #pragma unroll
            for (int i = 0; i < 4; i++) {
                int rg = m0 + wm + m * 16 + r4 + i;
                float v = acc[m][n][i] + bias;
                if (MODE == 0) obf[(size_t)rg * N + cg] = f2bf(v);
                else           of[(size_t)rg * N + cg] = v;
            }
        }
    }
}

// ---------------- per-position head-axis attention -------------------------
// att[h][g] = softmax_g( q[h]·k[g] / 8 );  hid[h][d] = sum_g att[h][g] v[g][d]
__global__ __launch_bounds__(256) void attn_kernel(const ushort* __restrict__ qkv,
                                                   ushort* __restrict__ hid) {
    const int lane = threadIdx.x & 63;
    const size_t pos = (size_t)blockIdx.x * 4 + (threadIdx.x >> 6);
    const ushort* base = qkv + pos * 1536;
    const int h = lane >> 3, g = lane & 7;
    const ushort* qp = base + h * 64;
    const ushort* kp = base + 512 + g * 64;
    float s = 0.f;
    #pragma unroll
    for (int dc = 0; dc < 8; dc++) {
        short8 q8 = *(const short8*)(qp + dc * 8);
        short8 k8 = *(const short8*)(kp + dc * 8);
        #pragma unroll
        for (int j = 0; j < 8; j++) s += bf2f((ushort)q8[j]) * bf2f((ushort)k8[j]);
    }
    s *= 0.125f;  // 1/sqrt(64)
    float mx = s;
    #pragma unroll
    for (int o = 1; o < 8; o <<= 1) mx = fmaxf(mx, __shfl_xor(mx, o));
    float e = __expf(s - mx);
    float den = e;
    #pragma unroll
    for (int o = 1; o < 8; o <<= 1) den += __shfl_xor(den, o);
    float att = e / den;
    float o8[8];
    #pragma unroll
    for (int j = 0; j < 8; j++) o8[j] = 0.f;
    const ushort* vp = base + 1024 + (lane & 7) * 8;
    #pragma unroll
    for (int gg = 0; gg < 8; gg++) {
        float a = __shfl(att, (lane & 56) | gg);
        short8 v8 = *(const short8*)(vp + gg * 64);
        #pragma unroll
        for (int j = 0; j < 8; j++) o8[j] += a * bf2f((ushort)v8[j]);
    }
    // c = h*64 + (lane&7)*8 + j == lane*8 + j -> fully coalesced 16B store
    short8 ov;
    #pragma unroll
    for (int j = 0; j < 8; j++) ov[j] = (short)f2bf(o8[j]);
    *(short8*)(hid + pos * 512 + lane * 8) = ov;
}

// ---------------- LN(residual): x = bf16(LN(tmp + x)) ----------------------
__global__ __launch_bounds__(256) void ln_kernel(const float* __restrict__ tmp,
                                                 ushort* __restrict__ xrow,
                                                 const float* __restrict__ gw,
                                                 const float* __restrict__ bw) {
    const int lane = threadIdx.x & 63;
    const size_t row = (size_t)blockIdx.x * 4 + (threadIdx.x >> 6);
    const float* tp = tmp + row * 512 + lane * 8;
    ushort* xp = xrow + row * 512 + lane * 8;
    float4 t0 = *(const float4*)tp, t1 = *(const float4*)(tp + 4);
    short8 xv = *(const short8*)xp;
    float v[8];
    #pragma unroll
    for (int j = 0; j < 8; j++) v[j] = bf2f((ushort)xv[j]);
    v[0] += t0.x; v[1] += t0.y; v[2] += t0.z; v[3] += t0.w;
    v[4] += t1.x; v[5] += t1.y; v[6] += t1.z; v[7] += t1.w;
    float s = 0.f, ss = 0.f;
    #pragma unroll
    for (int j = 0; j < 8; j++) { s += v[j]; ss += v[j] * v[j]; }
    #pragma unroll
    for (int o = 32; o > 0; o >>= 1) { s += __shfl_xor(s, o); ss += __shfl_xor(ss, o); }
    float mean = s * (1.f / 512.f);
    float var = ss * (1.f / 512.f) - mean * mean;
    float rstd = rsqrtf(var + 1e-5f);
    const float* gp = gw + lane * 8;
    const float* bp = bw + lane * 8;
    float4 g0 = *(const float4*)gp, g1 = *(const float4*)(gp + 4);
    float4 b0 = *(const float4*)bp, b1 = *(const float4*)(bp + 4);
    float gg[8] = {g0.x, g0.y, g0.z, g0.w, g1.x, g1.y, g1.z, g1.w};
    float bb[8] = {b0.x, b0.y, b0.z, b0.w, b1.x, b1.y, b1.z, b1.w};
    short8 hv;
    #pragma unroll
    for (int j = 0; j < 8; j++)
        hv[j] = (short)f2bf((v[j] - mean) * rstd * gg[j] + bb[j]);
    *(short8*)xp = hv;
}

// ---------------- logits: out = x @ W_lm + b_lm (f32, N=13) ----------------
__global__ __launch_bounds__(64) void logits_kernel(const ushort* __restrict__ x,
                                                    const float* __restrict__ Wlm,
                                                    const float* __restrict__ blm,
                                                    float* __restrict__ out) {
    const int lane = threadIdx.x;
    const size_t bt = blockIdx.x;
    short8 xv = *(const short8*)(x + bt * 512 + lane * 8);
    float p[13];
    #pragma unroll
    for (int v = 0; v < 13; v++) p[v] = 0.f;
    #pragma unroll
    for (int j = 0; j < 8; j++) {
        int k = lane * 8 + j;
        const float* wr = Wlm + (size_t)k * 13;
        float xf = bf2f((ushort)xv[j]);
        #pragma unroll
        for (int v = 0; v < 13; v++) p[v] += xf * wr[v];
    }
    #pragma unroll
    for (int v = 0; v < 13; v++) {
        float t = p[v];
        #pragma unroll
        for (int o = 32; o > 0; o >>= 1) t += __shfl_xor(t, o);
        p[v] = t;
    }
    if (lane == 0) {
        #pragma unroll
        for (int v = 0; v < 13; v++) out[bt * 13 + v] = p[v] + blm[v];
    }
}

// ---------------- loss over (b, t=127) rows --------------------------------
__global__ void loss_kernel(const float* __restrict__ logits,
                            const int* __restrict__ label, float* __restrict__ out) {
    const int tid = threadIdx.x;
    float acc = 0.f;
    for (int b = tid; b < 512; b += 256) {
        const float* lg = logits + ((size_t)b * 128 + 127) * 13;
        float mx = lg[0];
        #pragma unroll
        for (int v = 1; v < 13; v++) mx = fmaxf(mx, lg[v]);
        float den = 0.f;
        #pragma unroll
        for (int v = 0; v < 13; v++) den += expf(lg[v] - mx);
        int lab = label[b];
        acc += -(lg[lab] - mx - logf(den));
    }
    #pragma unroll
    for (int o = 32; o > 0; o >>= 1) acc += __shfl_xor(acc, o);
    __shared__ float red[4];
    if ((tid & 63) == 0) red[tid >> 6] = acc;
    __syncthreads();
    if (tid == 0) out[0] = (red[0] + red[1] + red[2] + red[3]) * (1.f / 512.f);
}

// ---------------------------------------------------------------------------
extern "C" void kernel_launch(void* const* d_in, const int* in_sizes, int n_in,
                              void* d_out, int out_size, void* d_ws, size_t ws_size,
                              hipStream_t stream) {
    const int*   tok   = (const int*)d_in[0];
    const int*   label = (const int*)d_in[1];
    const float* wte   = (const float*)d_in[2];
    const float* wpe   = (const float*)d_in[3];
    const float* Wq    = (const float*)d_in[4];
    const float* bq    = (const float*)d_in[5];
    const float* Wk    = (const float*)d_in[6];
    const float* bk    = (const float*)d_in[7];
    const float* Wv    = (const float*)d_in[8];
    const float* bv    = (const float*)d_in[9];
    const float* Wo    = (const float*)d_in[10];
    const float* bo    = (const float*)d_in[11];
    const float* ln_g  = (const float*)d_in[12];
    const float* ln_b  = (const float*)d_in[13];
    const float* Wlm   = (const float*)d_in[14];
    const float* blm   = (const float*)d_in[15];
    float* out = (float*)d_out;

    char* ws = (char*)d_ws;
    ushort* xbf   = (ushort*)(ws);                 // 67,108,864 B
    ushort* wqkvT = (ushort*)(ws + 67108864);      //  9,437,184 B
    ushort* woT   = (ushort*)(ws + 76546048);      //  3,145,728 B
    const size_t off_dyn = 79691776;

    // choose chunk rows R: qkv_c 3072B/row + tmp_c 2048B/row + hid_c 1024B/row
    int R = 65536;
    while (R > 1024 && off_dyn + (size_t)R * 6144 > ws_size) R >>= 1;
    const int nchunk = 65536 / R;
    ushort* qkv_c = (ushort*)(ws + off_dyn);
    float*  tmp_c = (float*) (ws + off_dyn + (size_t)R * 3072);
    ushort* hid_c = (ushort*)(ws + off_dyn + (size_t)R * 3072 + (size_t)R * 2048);

    prep_weights<<<24576, 256, 0, stream>>>(Wq, Wk, Wv, Wo, wqkvT, woT);
    embed_kernel<<<16384, 256, 0, stream>>>(tok, wte, wpe, xbf);

    for (int l = 0; l < 6; l++) {
        for (int c = 0; c < nchunk; c++) {
            const size_t base = (size_t)c * R;
            gemm_kernel<0><<<dim3(R / 128, 12), 256, 0, stream>>>(
                xbf + base * 512, wqkvT + (size_t)l * 1536 * 512, 1536,
                bq + l * 512, bk + l * 512, bv + l * 512, qkv_c, nullptr);
            attn_kernel<<<R / 4, 256, 0, stream>>>(qkv_c, hid_c);
            gemm_kernel<1><<<dim3(R / 128, 4), 256, 0, stream>>>(
                hid_c, woT + (size_t)l * 512 * 512, 512,
                bo + l * 512, nullptr, nullptr, nullptr, tmp_c);
            ln_kernel<<<R / 4, 256, 0, stream>>>(tmp_c, xbf + base * 512,
                                                 ln_g + l * 512, ln_b + l * 512);
        }
    }

    logits_kernel<<<65536, 64, 0, stream>>>(xbf, Wlm, blm, out);
    loss_kernel<<<1, 256, 0, stream>>>(out, label, out + 851968);
}

// Round 3
// 2200.258 us; speedup vs baseline: 1.1476x; 1.1476x over previous
//
#include <hip/hip_runtime.h>
#include <hip/hip_bf16.h>
#include <cstdint>
#include <cstddef>

// ---------------------------------------------------------------------------
// Transformer_78941498901000 — round 2: fused proj+LN, fast logits
// B=512 T=128 C=512 H=8 D=64 L=6 V=13, BT=65536
// d_out = logits f32 [851968] ++ loss f32 [1]
//
// ws layout (bytes):
//   x_bf  @ 0          : bf16 [BT,512]       67,108,864   (residual stream)
//   wqkvT @ 67,108,864 : bf16 [L][1536][512]  9,437,184   (n-major, k-minor)
//   woT   @ 76,546,048 : bf16 [L][512][512]   3,145,728
//   dyn   @ 79,691,776 : per-chunk qkv_c (3072 B/row) | hid_c (1024 B/row)
// R = largest {65536..1024} with 79,691,776 + 4096*R <= ws_size
// ---------------------------------------------------------------------------

typedef __attribute__((ext_vector_type(8))) short short8;
typedef __attribute__((ext_vector_type(4))) float f32x4;

__device__ __forceinline__ float bf2f(ushort u) {
    return __uint_as_float(((unsigned int)u) << 16);
}
__device__ __forceinline__ ushort f2bf(float f) {
    unsigned int x = __float_as_uint(f);
    unsigned int r = (x + 0x7fffu + ((x >> 16) & 1u)) >> 16;  // RNE
    return (ushort)r;
}

// ---------------- weight prep: f32 [K][N] -> bf16 [N][K] -------------------
__global__ void prep_weights(const float* __restrict__ Wq, const float* __restrict__ Wk,
                             const float* __restrict__ Wv, const float* __restrict__ Wo,
                             ushort* __restrict__ wqkvT, ushort* __restrict__ woT) {
    const int QKV_TOT = 6 * 1536 * 512;   // 4,718,592
    const int O_TOT   = 6 * 512 * 512;    // 1,572,864
    size_t idx = (size_t)blockIdx.x * 256 + threadIdx.x;
    if (idx < (size_t)QKV_TOT) {
        int k = (int)(idx & 511);
        int n = (int)((idx >> 9) % 1536);
        int l = (int)(idx / (1536 * 512));
        size_t base = (size_t)l * 512 * 512 + (size_t)k * 512;
        float v;
        if (n < 512)        v = Wq[base + n];
        else if (n < 1024)  v = Wk[base + (n - 512)];
        else                v = Wv[base + (n - 1024)];
        wqkvT[idx] = f2bf(v);
    } else if (idx < (size_t)(QKV_TOT + O_TOT)) {
        size_t j = idx - QKV_TOT;
        int k = (int)(j & 511);
        int n = (int)((j >> 9) & 511);
        int l = (int)(j / (512 * 512));
        woT[j] = f2bf(Wo[(size_t)l * 512 * 512 + (size_t)k * 512 + n]);
    }
}

// ---------------- embedding: x = bf16(wte[tok] + wpe[t]) -------------------
__global__ __launch_bounds__(256) void embed_kernel(const int* __restrict__ tok,
                                                    const float* __restrict__ wte,
                                                    const float* __restrict__ wpe,
                                                    ushort* __restrict__ xbf) {
    size_t idx = (size_t)blockIdx.x * 256 + threadIdx.x;  // one short8 per thread
    size_t row = idx >> 6;              // 64 chunks of 8 per row
    int c8 = (int)(idx & 63);
    int t = (int)(row & 127);
    int v = tok[row];
    const float* ep = wte + (size_t)v * 512 + c8 * 8;
    const float* pp = wpe + (size_t)t * 512 + c8 * 8;
    float4 e0 = *(const float4*)ep, e1 = *(const float4*)(ep + 4);
    float4 p0 = *(const float4*)pp, p1 = *(const float4*)(pp + 4);
    float s[8] = {e0.x + p0.x, e0.y + p0.y, e0.z + p0.z, e0.w + p0.w,
                  e1.x + p1.x, e1.y + p1.y, e1.z + p1.z, e1.w + p1.w};
    short8 o;
    #pragma unroll
    for (int j = 0; j < 8; j++) o[j] = (short)f2bf(s[j]);
    *(short8*)(xbf + row * 512 + c8 * 8) = o;
}

// ---------------- QKV GEMM: qkv = A[M,512] @ Bt[1536,512]^T + bias ---------
#define BM 128
#define BN 128
#define BKT 64

__global__ __launch_bounds__(256) void gemm_qkv_kernel(
    const ushort* __restrict__ A, const ushort* __restrict__ Bt,
    const float* __restrict__ b0, const float* __restrict__ b1,
    const float* __restrict__ b2, ushort* __restrict__ obf) {
    __shared__ alignas(16) ushort As[BM * BKT];
    __shared__ alignas(16) ushort Bs[BN * BKT];
    const int tid = threadIdx.x;
    const int lane = tid & 63;
    const int wave = tid >> 6;
    const int m0 = blockIdx.x * BM;
    const int n0 = blockIdx.y * BN;
    const int wm = (wave >> 1) * 64;
    const int wn = (wave & 1) * 64;
    const int r = lane & 15;
    const int kq = (lane >> 4) * 8;
    f32x4 acc[4][4] = {};

    for (int k0 = 0; k0 < 512; k0 += BKT) {
        #pragma unroll
        for (int i = 0; i < 4; i++) {
            int ch = tid + i * 256;          // 1024 chunks of 16B per tile
            int row = ch >> 3, c8 = ch & 7;
            short8 va = *(const short8*)(A  + (size_t)(m0 + row) * 512 + k0 + c8 * 8);
            short8 vb = *(const short8*)(Bt + (size_t)(n0 + row) * 512 + k0 + c8 * 8);
            int boff = (row * 128 + c8 * 16) ^ ((row & 7) << 4);  // XOR swizzle (G4)
            *(short8*)((char*)As + boff) = va;
            *(short8*)((char*)Bs + boff) = vb;
        }
        __syncthreads();
        #pragma unroll
        for (int kk = 0; kk < BKT; kk += 32) {
            short8 af[4], bfr[4];
            #pragma unroll
            for (int m = 0; m < 4; m++) {
                int row = wm + m * 16 + r;
                int boff = (row * 128 + (kk + kq) * 2) ^ ((row & 7) << 4);
                af[m] = *(const short8*)((const char*)As + boff);
            }
            #pragma unroll
            for (int n = 0; n < 4; n++) {
                int row = wn + n * 16 + r;
                int boff = (row * 128 + (kk + kq) * 2) ^ ((row & 7) << 4);
                bfr[n] = *(const short8*)((const char*)Bs + boff);
            }
            #pragma unroll
            for (int m = 0; m < 4; m++)
                #pragma unroll
                for (int n = 0; n < 4; n++)
                    acc[m][n] = __builtin_amdgcn_mfma_f32_16x16x32_bf16(
                        af[m], bfr[n], acc[m][n], 0, 0, 0);
        }
        __syncthreads();
    }
    const int r4 = (lane >> 4) * 4;
    const int cc = lane & 15;
    #pragma unroll
    for (int m = 0; m < 4; m++) {
        #pragma unroll
        for (int n = 0; n < 4; n++) {
            int cg = n0 + wn + n * 16 + cc;
            float bias = (cg < 512) ? b0[cg] : (cg < 1024) ? b1[cg - 512] : b2[cg - 1024];
            #pragma unroll
            for (int i = 0; i < 4; i++) {
                int rg = m0 + wm + m * 16 + r4 + i;
                obf[(size_t)rg * 1536 + cg] = f2bf(acc[m][n][i] + bias);
            }
        }
    }
}

// ---------------- per-position head-axis attention -------------------------
// att[h][g] = softmax_g( q[h]·k[g] / 8 );  hid[h][d] = sum_g att[h][g] v[g][d]
__global__ __launch_bounds__(256) void attn_kernel(const ushort* __restrict__ qkv,
                                                   ushort* __restrict__ hid) {
    const int lane = threadIdx.x & 63;
    const size_t pos = (size_t)blockIdx.x * 4 + (threadIdx.x >> 6);
    const ushort* base = qkv + pos * 1536;
    const int h = lane >> 3, g = lane & 7;
    const ushort* qp = base + h * 64;
    const ushort* kp = base + 512 + g * 64;
    float s = 0.f;
    #pragma unroll
    for (int dc = 0; dc < 8; dc++) {
        short8 q8 = *(const short8*)(qp + dc * 8);
        short8 k8 = *(const short8*)(kp + dc * 8);
        #pragma unroll
        for (int j = 0; j < 8; j++) s += bf2f((ushort)q8[j]) * bf2f((ushort)k8[j]);
    }
    s *= 0.125f;  // 1/sqrt(64)
    float mx = s;
    #pragma unroll
    for (int o = 1; o < 8; o <<= 1) mx = fmaxf(mx, __shfl_xor(mx, o));
    float e = __expf(s - mx);
    float den = e;
    #pragma unroll
    for (int o = 1; o < 8; o <<= 1) den += __shfl_xor(den, o);
    float att = e / den;
    float o8[8];
    #pragma unroll
    for (int j = 0; j < 8; j++) o8[j] = 0.f;
    const ushort* vp = base + 1024 + (lane & 7) * 8;
    #pragma unroll
    for (int gg = 0; gg < 8; gg++) {
        float a = __shfl(att, (lane & 56) | gg);
        short8 v8 = *(const short8*)(vp + gg * 64);
        #pragma unroll
        for (int j = 0; j < 8; j++) o8[j] += a * bf2f((ushort)v8[j]);
    }
    // c = h*64 + (lane&7)*8 + j == lane*8 + j -> fully coalesced 16B store
    short8 ov;
    #pragma unroll
    for (int j = 0; j < 8; j++) ov[j] = (short)f2bf(o8[j]);
    *(short8*)(hid + pos * 512 + lane * 8) = ov;
}

// ---------------- fused proj + bias + residual + LayerNorm -----------------
// xrow[M,512] = bf16( LN( A[M,512] @ Bt[512,512]^T + bo + xrow ) )
// BM=128, BN=512 (full row), BK=64, 512 threads (8 waves: 2 rows x 4 cols)
__global__ __launch_bounds__(512) void proj_ln_kernel(
    const ushort* __restrict__ A, const ushort* __restrict__ Bt,
    const float* __restrict__ bo_, const float* __restrict__ gw,
    const float* __restrict__ bw, ushort* __restrict__ xrow) {
    __shared__ alignas(16) ushort As[128 * 64];   // 16 KB
    __shared__ alignas(16) ushort Bs[512 * 64];   // 64 KB
    __shared__ float ps[4][128], pss[4][128];     //  4 KB
    const int tid = threadIdx.x;
    const int lane = tid & 63;
    const int wave = tid >> 6;            // 0..7
    const int m0 = blockIdx.x * 128;
    const int wm = (wave >> 2) * 64;      // 0 | 64
    const int wn = (wave & 3) * 128;      // 0 | 128 | 256 | 384
    const int r = lane & 15;
    const int kq = (lane >> 4) * 8;
    f32x4 acc[4][8] = {};

    for (int k0 = 0; k0 < 512; k0 += 64) {
        #pragma unroll
        for (int i = 0; i < 2; i++) {     // stage A: 1024 16B-chunks
            int ch = tid + i * 512;
            int row = ch >> 3, c8 = ch & 7;
            short8 va = *(const short8*)(A + (size_t)(m0 + row) * 512 + k0 + c8 * 8);
            int boff = (row * 128 + c8 * 16) ^ ((row & 7) << 4);
            *(short8*)((char*)As + boff) = va;
        }
        #pragma unroll
        for (int i = 0; i < 8; i++) {     // stage B: 4096 16B-chunks
            int ch = tid + i * 512;
            int row = ch >> 3, c8 = ch & 7;
            short8 vb = *(const short8*)(Bt + (size_t)row * 512 + k0 + c8 * 8);
            int boff = (row * 128 + c8 * 16) ^ ((row & 7) << 4);
            *(short8*)((char*)Bs + boff) = vb;
        }
        __syncthreads();
        #pragma unroll
        for (int kk = 0; kk < 64; kk += 32) {
            short8 af[4];
            #pragma unroll
            for (int m = 0; m < 4; m++) {
                int row = wm + m * 16 + r;
                int boff = (row * 128 + (kk + kq) * 2) ^ ((row & 7) << 4);
                af[m] = *(const short8*)((const char*)As + boff);
            }
            #pragma unroll
            for (int n = 0; n < 8; n++) {
                int row = wn + n * 16 + r;
                int boff = (row * 128 + (kk + kq) * 2) ^ ((row & 7) << 4);
                short8 bf8 = *(const short8*)((const char*)Bs + boff);
                #pragma unroll
                for (int m = 0; m < 4; m++)
                    acc[m][n] = __builtin_amdgcn_mfma_f32_16x16x32_bf16(
                        af[m], bf8, acc[m][n], 0, 0, 0);
            }
        }
        __syncthreads();
    }
    // ---- epilogue: bias + residual, per-row stats, LN, bf16 store ----
    const int r4 = (lane >> 4) * 4;
    const int cc = lane & 15;
    float gv[8], bv8[8], bov[8];
    #pragma unroll
    for (int n = 0; n < 8; n++) {
        int col = wn + n * 16 + cc;
        gv[n] = gw[col]; bv8[n] = bw[col]; bov[n] = bo_[col];
    }
    #pragma unroll
    for (int m = 0; m < 4; m++) {
        #pragma unroll
        for (int i = 0; i < 4; i++) {
            int lrow = wm + m * 16 + r4 + i;
            float s = 0.f, ss = 0.f;
            #pragma unroll
            for (int n = 0; n < 8; n++) {
                int col = wn + n * 16 + cc;
                float v = acc[m][n][i] + bov[n]
                        + bf2f(xrow[(size_t)(m0 + lrow) * 512 + col]);
                acc[m][n][i] = v;
                s += v; ss += v * v;
            }
            #pragma unroll
            for (int o = 1; o < 16; o <<= 1) {
                s += __shfl_xor(s, o); ss += __shfl_xor(ss, o);
            }
            if (cc == 0) { ps[wave & 3][lrow] = s; pss[wave & 3][lrow] = ss; }
        }
    }
    __syncthreads();
    #pragma unroll
    for (int m = 0; m < 4; m++) {
        #pragma unroll
        for (int i = 0; i < 4; i++) {
            int lrow = wm + m * 16 + r4 + i;
            float s  = ps[0][lrow] + ps[1][lrow] + ps[2][lrow] + ps[3][lrow];
            float ss = pss[0][lrow] + pss[1][lrow] + pss[2][lrow] + pss[3][lrow];
            float mean = s * (1.f / 512.f);
            float var = ss * (1.f / 512.f) - mean * mean;
            float rstd = rsqrtf(var + 1e-5f);
            #pragma unroll
            for (int n = 0; n < 8; n++) {
                int col = wn + n * 16 + cc;
                float y = (acc[m][n][i] - mean) * rstd * gv[n] + bv8[n];
                xrow[(size_t)(m0 + lrow) * 512 + col] = f2bf(y);
            }
        }
    }
}

// ---------------- logits: out = x @ W_lm + b_lm (f32, N=13) ----------------
// 256 threads, 32 rows/block; Wlm staged in LDS as [j][lane][13] (stride 13
// -> bank-conflict-free). One row per wave per iteration, coalesced short8.
__global__ __launch_bounds__(256) void logits_kernel(const ushort* __restrict__ x,
                                                     const float* __restrict__ Wlm,
                                                     const float* __restrict__ blm,
                                                     float* __restrict__ out) {
    __shared__ float wl[8 * 64 * 13];   // 26,624 B
    const int tid = threadIdx.x;
    for (int k = tid; k < 512; k += 256) {
        int dst = ((k & 7) * 64 + (k >> 3)) * 13;
        #pragma unroll
        for (int v = 0; v < 13; v++) wl[dst + v] = Wlm[k * 13 + v];
    }
    __syncthreads();
    const int lane = tid & 63;
    const int w = tid >> 6;
    float bl[13];
    #pragma unroll
    for (int v = 0; v < 13; v++) bl[v] = blm[v];
    for (int it = 0; it < 8; it++) {
        size_t row = (size_t)blockIdx.x * 32 + it * 4 + w;
        short8 xv = *(const short8*)(x + row * 512 + lane * 8);
        float p[13];
        #pragma unroll
        for (int v = 0; v < 13; v++) p[v] = 0.f;
        #pragma unroll
        for (int j = 0; j < 8; j++) {
            float xf = bf2f((ushort)xv[j]);
            const float* wr = wl + (j * 64 + lane) * 13;
            #pragma unroll
            for (int v = 0; v < 13; v++) p[v] += xf * wr[v];
        }
        #pragma unroll
        for (int v = 0; v < 13; v++) {
            #pragma unroll
            for (int o = 32; o > 0; o >>= 1) p[v] += __shfl_xor(p[v], o);
        }
        if (lane == 0) {
            #pragma unroll
            for (int v = 0; v < 13; v++) out[row * 13 + v] = p[v] + bl[v];
        }
    }
}

// ---------------- loss over (b, t=127) rows --------------------------------
__global__ void loss_kernel(const float* __restrict__ logits,
                            const int* __restrict__ label, float* __restrict__ out) {
    const int tid = threadIdx.x;
    float acc = 0.f;
    for (int b = tid; b < 512; b += 256) {
        const float* lg = logits + ((size_t)b * 128 + 127) * 13;
        float mx = lg[0];
        #pragma unroll
        for (int v = 1; v < 13; v++) mx = fmaxf(mx, lg[v]);
        float den = 0.f;
        #pragma unroll
        for (int v = 0; v < 13; v++) den += expf(lg[v] - mx);
        int lab = label[b];
        acc += -(lg[lab] - mx - logf(den));
    }
    #pragma unroll
    for (int o = 32; o > 0; o >>= 1) acc += __shfl_xor(acc, o);
    __shared__ float red[4];
    if ((tid & 63) == 0) red[tid >> 6] = acc;
    __syncthreads();
    if (tid == 0) out[0] = (red[0] + red[1] + red[2] + red[3]) * (1.f / 512.f);
}

// ---------------------------------------------------------------------------
extern "C" void kernel_launch(void* const* d_in, const int* in_sizes, int n_in,
                              void* d_out, int out_size, void* d_ws, size_t ws_size,
                              hipStream_t stream) {
    const int*   tok   = (const int*)d_in[0];
    const int*   label = (const int*)d_in[1];
    const float* wte   = (const float*)d_in[2];
    const float* wpe   = (const float*)d_in[3];
    const float* Wq    = (const float*)d_in[4];
    const float* bq    = (const float*)d_in[5];
    const float* Wk    = (const float*)d_in[6];
    const float* bk    = (const float*)d_in[7];
    const float* Wv    = (const float*)d_in[8];
    const float* bv    = (const float*)d_in[9];
    const float* Wo    = (const float*)d_in[10];
    const float* bo    = (const float*)d_in[11];
    const float* ln_g  = (const float*)d_in[12];
    const float* ln_b  = (const float*)d_in[13];
    const float* Wlm   = (const float*)d_in[14];
    const float* blm   = (const float*)d_in[15];
    float* out = (float*)d_out;

    char* ws = (char*)d_ws;
    ushort* xbf   = (ushort*)(ws);                 // 67,108,864 B
    ushort* wqkvT = (ushort*)(ws + 67108864);      //  9,437,184 B
    ushort* woT   = (ushort*)(ws + 76546048);      //  3,145,728 B
    const size_t off_dyn = 79691776;

    // chunk rows R: qkv_c 3072 B/row + hid_c 1024 B/row
    int R = 65536;
    while (R > 1024 && off_dyn + (size_t)R * 4096 > ws_size) R >>= 1;
    const int nchunk = 65536 / R;
    ushort* qkv_c = (ushort*)(ws + off_dyn);
    ushort* hid_c = (ushort*)(ws + off_dyn + (size_t)R * 3072);

    prep_weights<<<24576, 256, 0, stream>>>(Wq, Wk, Wv, Wo, wqkvT, woT);
    embed_kernel<<<16384, 256, 0, stream>>>(tok, wte, wpe, xbf);

    for (int l = 0; l < 6; l++) {
        for (int c = 0; c < nchunk; c++) {
            const size_t base = (size_t)c * R;
            gemm_qkv_kernel<<<dim3(R / 128, 12), 256, 0, stream>>>(
                xbf + base * 512, wqkvT + (size_t)l * 1536 * 512,
                bq + l * 512, bk + l * 512, bv + l * 512, qkv_c);
            attn_kernel<<<R / 4, 256, 0, stream>>>(qkv_c, hid_c);
            proj_ln_kernel<<<R / 128, 512, 0, stream>>>(
                hid_c, woT + (size_t)l * 512 * 512, bo + l * 512,
                ln_g + l * 512, ln_b + l * 512, xbf + base * 512);
        }
    }

    logits_kernel<<<2048, 256, 0, stream>>>(xbf, Wlm, blm, out);
    loss_kernel<<<1, 256, 0, stream>>>(out, label, out + 851968);
}